// Round 6
// baseline (398.467 us; speedup 1.0000x reference)
//
#include <hip/hip_runtime.h>
#include <hip/hip_bf16.h>
#include <cmath>

#define D_MODEL 1024
#define NHEADS  16
#define DK      64
#define BATCH   32
#define SEQ     512
#define M_TOTAL (BATCH * SEQ)   // 16384
#define LIN_EPS 1e-6f

typedef __attribute__((ext_vector_type(8))) short short8;
typedef __attribute__((ext_vector_type(4))) short short4v;
typedef __attribute__((ext_vector_type(4))) float floatx4;

__device__ inline short f2bf(float f) {
    __hip_bfloat16 h = __float2bfloat16(f);
    return *reinterpret_cast<short*>(&h);
}
__device__ inline float bf2f(short s) {
    unsigned int u = ((unsigned int)(unsigned short)s) << 16;
    union { unsigned int u; float f; } c; c.u = u;
    return c.f;
}

#define GLL16(gptr, lptr)                                                      \
    __builtin_amdgcn_global_load_lds(                                          \
        (const __attribute__((address_space(1))) unsigned int*)(gptr),         \
        (__attribute__((address_space(3))) unsigned int*)(lptr), 16, 0, 0)

#define MFMA16(a, b, c) __builtin_amdgcn_mfma_f32_16x16x32_bf16((a), (b), (c), 0, 0, 0)

// ---------------------------------------------------------------------------
// fp32 -> bf16 cast
// ---------------------------------------------------------------------------
__global__ __launch_bounds__(256)
void cast_bf16(const float* __restrict__ in, short* __restrict__ out, int n4)
{
    int i = blockIdx.x * 256 + threadIdx.x;
    if (i >= n4) return;
    float4 f = *(const float4*)&in[(size_t)i * 4];
    short4v s;
    s.x = f2bf(f.x); s.y = f2bf(f.y); s.z = f2bf(f.z); s.w = f2bf(f.w);
    *(short4v*)&out[(size_t)i * 4] = s;
}

// ---------------------------------------------------------------------------
// All four W[K][N] fp32 -> Wt[N][K] bf16; z selects matrix.
// ---------------------------------------------------------------------------
__global__ __launch_bounds__(256)
void transpose_w4(const float* __restrict__ W0, const float* __restrict__ W1,
                  const float* __restrict__ W2, const float* __restrict__ W3,
                  short* __restrict__ WtBase)
{
    __shared__ float tile[32][33];
    const int z = blockIdx.z;
    const float* W = (z == 0) ? W0 : (z == 1) ? W1 : (z == 2) ? W2 : W3;
    short* Wt = WtBase + (size_t)z * D_MODEL * D_MODEL;
    const int tx = threadIdx.x, ty = threadIdx.y;   // 32 x 8
    const int nb = blockIdx.x * 32, kb = blockIdx.y * 32;
    #pragma unroll
    for (int r = 0; r < 32; r += 8)
        tile[ty + r][tx] = W[(size_t)(kb + ty + r) * D_MODEL + nb + tx];
    __syncthreads();
    #pragma unroll
    for (int r = 0; r < 32; r += 8)
        Wt[(size_t)(nb + ty + r) * D_MODEL + kb + tx] = f2bf(tile[tx][ty + r]);
}

// ---------------------------------------------------------------------------
// 256x256 GEMM, BK=32, QUAD-buffered LDS, counted vmcnt, L2-supertiled
// block order (R5-verified: 122us, 845 TF, 0 bank conflicts). UNCHANGED.
// MODE 0: C += bias[q|k|v]; seg<2 -> elu+1; bf16 store to [seg][B,H,N,DK].
// MODE 1: C += bias; fp32 store row-major [M][1024].
// ---------------------------------------------------------------------------
template<int MODE>
__global__ __launch_bounds__(512, 2)
void gemm256(const short* __restrict__ A, const short* __restrict__ Wt,
             const float* __restrict__ bq, const float* __restrict__ bk,
             const float* __restrict__ bv, short* __restrict__ outB,
             float* __restrict__ outF)
{
    constexpr int K   = 1024;
    constexpr int NBX = (MODE == 0) ? 12 : 4;   // col-tiles of 256
    constexpr int NT  = 32;                     // K-tiles of 32
    __shared__ short lds[65536];                // 128 KiB = 4 x 16384 shorts

    const int t    = threadIdx.x;
    const int wave = t >> 6;
    const int lane = t & 63;
    const int wm   = wave >> 2;                 // 0..1  -> rows wm*128
    const int wn   = wave & 3;                  // 0..3  -> cols wn*64

    // XCD-aware + L2-supertiled mapping (R5).
    const int bid = (int)blockIdx.x;
    const int xcd = bid & 7;
    const int loc = bid >> 3;
    const int g   = loc >> 5;                   // bx group
    const int r   = loc & 31;
    const int by  = xcd * 8 + (r >> 2);
    const int bx  = g * 4 + (r & 3);
    const int rowBase = by * 256;
    const int colBase = bx * 256;

    // fragment read addressing (T2 read-side swizzle)
    const int laneM = lane & 15;
    const int gq    = lane >> 4;
    const int co    = ((gq ^ ((laneM >> 1) & 3)) << 3);        // shorts
    const int aoff  = (wm * 128 + laneM) * 32 + co;            // A region +0
    const int boff  = 8192 + (wn * 64 + laneM) * 32 + co;      // B region +8192

    // staging addressing (T2 inverse swizzle on global source)
    const int stRow = t >> 2;                                   // 0..127
    const int stCol = (((t & 3) ^ ((t >> 3) & 3)) << 3);        // shorts
    const short* aSt = A  + (size_t)(rowBase + stRow) * K + stCol;
    const short* bSt = Wt + (size_t)(colBase + stRow) * K + stCol;
    const short* aSt2 = aSt + (size_t)128 * K;
    const short* bSt2 = bSt + (size_t)128 * K;
    const int dT = t * 8;                                       // shorts

    floatx4 acc[8][4];
    #pragma unroll
    for (int i = 0; i < 8; i++)
        #pragma unroll
        for (int j = 0; j < 4; j++) acc[i][j] = (floatx4){0.f, 0.f, 0.f, 0.f};

    short8 a[8], b[4];

    // prologue: tiles 0,1,2 -> bufs 0,1,2
    #pragma unroll
    for (int tt = 0; tt < 3; ++tt) {
        const int bb = tt * 16384;
        GLL16(aSt  + tt * 32, &lds[bb + dT]);
        GLL16(aSt2 + tt * 32, &lds[bb + 4096 + dT]);
        GLL16(bSt  + tt * 32, &lds[bb + 8192 + dT]);
        GLL16(bSt2 + tt * 32, &lds[bb + 8192 + 4096 + dT]);
    }

    #pragma unroll
    for (int kt = 0; kt < NT; ++kt) {
        const int cb = (kt & 3) << 14;              // current buffer (shorts)
        const int sb = ((kt + 3) & 3) << 14;        // staging target

        if (kt <= NT - 3)      asm volatile("s_waitcnt vmcnt(8)" ::: "memory");
        else if (kt == NT - 2) asm volatile("s_waitcnt vmcnt(4)" ::: "memory");
        else                   asm volatile("s_waitcnt vmcnt(0)" ::: "memory");
        __builtin_amdgcn_s_barrier();
        __builtin_amdgcn_sched_barrier(0);

        if (kt + 3 < NT) {
            GLL16(aSt  + (kt + 3) * 32, &lds[sb + dT]);
            GLL16(aSt2 + (kt + 3) * 32, &lds[sb + 4096 + dT]);
            GLL16(bSt  + (kt + 3) * 32, &lds[sb + 8192 + dT]);
            GLL16(bSt2 + (kt + 3) * 32, &lds[sb + 8192 + 4096 + dT]);
        }

        b[0] = *(const short8*)&lds[cb + boff];
        b[1] = *(const short8*)&lds[cb + boff + 512];
        #pragma unroll
        for (int i = 0; i < 4; i++)
            a[i] = *(const short8*)&lds[cb + aoff + i * 512];

        __builtin_amdgcn_s_setprio(1);
        #pragma unroll
        for (int i = 0; i < 4; i++) {
            acc[i][0] = MFMA16(a[i], b[0], acc[i][0]);
            acc[i][1] = MFMA16(a[i], b[1], acc[i][1]);
        }

        b[2] = *(const short8*)&lds[cb + boff + 1024];
        b[3] = *(const short8*)&lds[cb + boff + 1536];
        #pragma unroll
        for (int i = 0; i < 4; i++)
            a[4 + i] = *(const short8*)&lds[cb + aoff + (4 + i) * 512];

        #pragma unroll
        for (int i = 0; i < 4; i++) {
            acc[i][2] = MFMA16(a[i], b[2], acc[i][2]);
            acc[i][3] = MFMA16(a[i], b[3], acc[i][3]);
        }
        #pragma unroll
        for (int i = 0; i < 4; i++) {
            acc[4 + i][0] = MFMA16(a[4 + i], b[0], acc[4 + i][0]);
            acc[4 + i][1] = MFMA16(a[4 + i], b[1], acc[4 + i][1]);
            acc[4 + i][2] = MFMA16(a[4 + i], b[2], acc[4 + i][2]);
            acc[4 + i][3] = MFMA16(a[4 + i], b[3], acc[4 + i][3]);
        }
        __builtin_amdgcn_s_setprio(0);
    }

    // ---------------- epilogue ----------------
    if (MODE == 0) {
        const int seg = colBase >> 10;
        const float* bias = (seg == 0) ? bq : (seg == 1) ? bk : bv;
        short* outSeg = outB + (size_t)seg * ((size_t)M_TOTAL * D_MODEL);
        #pragma unroll
        for (int i = 0; i < 8; i++) {
            const int r0 = rowBase + wm * 128 + i * 16 + gq * 4;
            #pragma unroll
            for (int j = 0; j < 4; j++) {
                const int cl = (colBase & 1023) + wn * 64 + j * 16 + laneM;
                const float bvv = bias[cl];
                const int h_ = cl >> 6;
                const int d_ = cl & 63;
                #pragma unroll
                for (int reg = 0; reg < 4; reg++) {
                    float val = acc[i][j][reg] + bvv;
                    if (seg < 2) val = (val > 0.f) ? val + 1.f : expf(val);
                    const int row = r0 + reg;
                    const int b_ = row >> 9;      // SEQ=512
                    const int n_ = row & 511;
                    outSeg[((size_t)((b_ * NHEADS + h_) * SEQ + n_)) * DK + d_] = f2bf(val);
                }
            }
        }
    } else {
        #pragma unroll
        for (int i = 0; i < 8; i++) {
            const int r0 = rowBase + wm * 128 + i * 16 + gq * 4;
            #pragma unroll
            for (int j = 0; j < 4; j++) {
                const int c = colBase + wn * 64 + j * 16 + laneM;
                const float bvv = bq[c];
                #pragma unroll
                for (int reg = 0; reg < 4; reg++)
                    outF[(size_t)(r0 + reg) * 1024 + c] = acc[i][j][reg] + bvv;
            }
        }
    }
}

// ---------------------------------------------------------------------------
// Linear attention per (b,h) — R6: phase-1 (KV, ksum) on MFMA.
//   KV[d][e] = sum_n kf[n][d] v[n][e]: per 32-n tile, stage kfT[64][n32] and
//   vT[64][n32] (transposed, stride 40 shorts, pack-2 ds_write_b32), then
//   A-frag = kfT row-major [d][n], B-frag = vT [e][n] — the exact proven
//   GEMM fragment pattern (C[m][n] = sum_k A[m][k]B[n][k]). 4 waves x one
//   16-e column; 4 MFMA/tile/wave. ksum via ones-B MFMA on wave 0.
//   fp32 accumulation throughout -> precision identical to VALU version.
//   Phase 2: VALU, vectorized (float4 ksum/qa/kv reads, d0-step-4).
// ---------------------------------------------------------------------------
__global__ __launch_bounds__(256)
void attn_kernel(const short* __restrict__ qf, const short* __restrict__ kf,
                 const short* __restrict__ v, short* __restrict__ attn)
{
    __shared__ short kfT[2][64 * 40];   // [d][stride 40], cols 0..31 used
    __shared__ short vT [2][64 * 40];
    __shared__ float kvS[64][68];
    __shared__ float ksumS[64];
    __shared__ float qS[64][68];

    const int bh = blockIdx.x;          // 0..511
    const int b  = bh >> 4;
    const int h  = bh & 15;
    const size_t base = (size_t)bh * SEQ * DK;
    const short* qfp = qf + base;
    const short* kfp = kf + base;
    const short* vp  = v  + base;

    const int t    = threadIdx.x;
    const int wave = t >> 6;
    const int lane = t & 63;
    const int fr   = lane & 15;         // frag row
    const int fg   = lane >> 4;         // frag k-group / acc row-group

    // phase-1 transpose-staging role: threads 0..127 kf, 128..255 v
    const int ts    = t & 127;
    const short* src = (t >> 7) ? vp : kfp;
    short* dstT0 = (t >> 7) ? &vT[0][0] : &kfT[0][0];
    short* dstT1 = (t >> 7) ? &vT[1][0] : &kfT[1][0];
    const int npair = ts & 15;          // n-pair within tile (n = npair*2)
    const int d0s   = (ts >> 4) * 8;    // d slice

    floatx4 accKV[4], accKS[4];
    #pragma unroll
    for (int m = 0; m < 4; ++m) {
        accKV[m] = (floatx4){0.f, 0.f, 0.f, 0.f};
        accKS[m] = (floatx4){0.f, 0.f, 0.f, 0.f};
    }
    short8 ones;
    #pragma unroll
    for (int j = 0; j < 8; ++j) ones[j] = (short)0x3F80;   // bf16 1.0

    short8 r0 = *(const short8*)&src[(size_t)(npair * 2) * DK + d0s];
    short8 r1 = *(const short8*)&src[(size_t)(npair * 2 + 1) * DK + d0s];

    #pragma unroll
    for (int tt = 0; tt < 16; ++tt) {
        short* dstT = (tt & 1) ? dstT1 : dstT0;
        #pragma unroll
        for (int j = 0; j < 8; ++j) {
            unsigned int pk = (unsigned int)(unsigned short)r0[j]
                            | ((unsigned int)(unsigned short)r1[j] << 16);
            *(unsigned int*)&dstT[(d0s + j) * 40 + npair * 2] = pk;
        }
        if (tt < 15) {
            const int n0 = (tt + 1) * 32;
            r0 = *(const short8*)&src[(size_t)(n0 + npair * 2) * DK + d0s];
            r1 = *(const short8*)&src[(size_t)(n0 + npair * 2 + 1) * DK + d0s];
        }
        __syncthreads();
        const short* kB = (tt & 1) ? &kfT[1][0] : &kfT[0][0];
        const short* vB = (tt & 1) ? &vT[1][0]  : &vT[0][0];
        short8 bf = *(const short8*)&vB[(wave * 16 + fr) * 40 + fg * 8];
        #pragma unroll
        for (int m = 0; m < 4; ++m) {
            short8 af = *(const short8*)&kB[(m * 16 + fr) * 40 + fg * 8];
            accKV[m] = MFMA16(af, bf, accKV[m]);
            if (wave == 0) accKS[m] = MFMA16(af, ones, accKS[m]);
        }
        // next iter writes the other buffer; buffer tt&1 is rewritten only at
        // tt+2, after the tt+1 barrier — by then all reads (consumed by the
        // MFMAs above, which precede that barrier) have completed.
    }

    // C/D layout: col = lane&15, row = (lane>>4)*4 + reg (verified mapping)
    #pragma unroll
    for (int m = 0; m < 4; ++m)
        #pragma unroll
        for (int reg = 0; reg < 4; ++reg)
            kvS[m * 16 + fg * 4 + reg][wave * 16 + fr] = accKV[m][reg];
    if (wave == 0 && fr == 0) {
        #pragma unroll
        for (int m = 0; m < 4; ++m)
            #pragma unroll
            for (int reg = 0; reg < 4; ++reg)
                ksumS[m * 16 + fg * 4 + reg] = accKS[m][reg];
    }

    // ---------------- phase 2: out = qf @ KV / (qf . ksum + eps) ----------
    const int tr = t >> 4;              // 0..15
    const int tc = t & 15;
    const int qlr = t >> 2;             // 0..63
    const int qlc = (t & 3) * 16;       // 0,16,32,48

    for (int n0 = 0; n0 < SEQ; n0 += 64) {
        __syncthreads();
        short8 q0 = *(const short8*)&qfp[(size_t)(n0 + qlr) * DK + qlc];
        short8 q1 = *(const short8*)&qfp[(size_t)(n0 + qlr) * DK + qlc + 8];
        float4 f0 = make_float4(bf2f(q0[0]), bf2f(q0[1]), bf2f(q0[2]), bf2f(q0[3]));
        float4 f1 = make_float4(bf2f(q0[4]), bf2f(q0[5]), bf2f(q0[6]), bf2f(q0[7]));
        float4 f2 = make_float4(bf2f(q1[0]), bf2f(q1[1]), bf2f(q1[2]), bf2f(q1[3]));
        float4 f3 = make_float4(bf2f(q1[4]), bf2f(q1[5]), bf2f(q1[6]), bf2f(q1[7]));
        *(float4*)&qS[qlr][qlc]      = f0;
        *(float4*)&qS[qlr][qlc + 4]  = f1;
        *(float4*)&qS[qlr][qlc + 8]  = f2;
        *(float4*)&qS[qlr][qlc + 12] = f3;
        __syncthreads();

        float4 o[4];
        float den[4];
        #pragma unroll
        for (int i = 0; i < 4; i++) {
            o[i] = make_float4(0.f, 0.f, 0.f, 0.f);
            den[i] = LIN_EPS;
        }
        #pragma unroll 4
        for (int d0 = 0; d0 < 64; d0 += 4) {
            float4 ks4 = *(const float4*)&ksumS[d0];
            float4 b0 = *(const float4*)&kvS[d0 + 0][tc * 4];
            float4 b1 = *(const float4*)&kvS[d0 + 1][tc * 4];
            float4 b2 = *(const float4*)&kvS[d0 + 2][tc * 4];
            float4 b3 = *(const float4*)&kvS[d0 + 3][tc * 4];
            #pragma unroll
            for (int i = 0; i < 4; i++) {
                float4 qa = *(const float4*)&qS[tr * 4 + i][d0];
                o[i].x += qa.x * b0.x + qa.y * b1.x + qa.z * b2.x + qa.w * b3.x;
                o[i].y += qa.x * b0.y + qa.y * b1.y + qa.z * b2.y + qa.w * b3.y;
                o[i].z += qa.x * b0.z + qa.y * b1.z + qa.z * b2.z + qa.w * b3.z;
                o[i].w += qa.x * b0.w + qa.y * b1.w + qa.z * b2.w + qa.w * b3.w;
                den[i] += qa.x * ks4.x + qa.y * ks4.y + qa.z * ks4.z + qa.w * ks4.w;
            }
        }
        #pragma unroll
        for (int i = 0; i < 4; i++) {
            const float inv = 1.f / den[i];
            const int n = n0 + tr * 4 + i;
            short* dst = attn + ((size_t)(b * SEQ + n)) * D_MODEL + h * DK;
            short4v s;
            s.x = f2bf(o[i].x * inv);
            s.y = f2bf(o[i].y * inv);
            s.z = f2bf(o[i].z * inv);
            s.w = f2bf(o[i].w * inv);
            *(short4v*)&dst[tc * 4] = s;
        }
    }
}

extern "C" void kernel_launch(void* const* d_in, const int* in_sizes, int n_in,
                              void* d_out, int out_size, void* d_ws, size_t ws_size,
                              hipStream_t stream)
{
    const float* x   = (const float*)d_in[0];
    const float* W_q = (const float*)d_in[1];
    const float* b_q = (const float*)d_in[2];
    const float* W_k = (const float*)d_in[3];
    const float* b_k = (const float*)d_in[4];
    const float* W_v = (const float*)d_in[5];
    const float* b_v = (const float*)d_in[6];
    const float* W_o = (const float*)d_in[7];
    const float* b_o = (const float*)d_in[8];
    float* out = (float*)d_out;

    const size_t MN = (size_t)M_TOTAL * D_MODEL;   // 16,777,216
    const size_t WN = (size_t)D_MODEL * D_MODEL;   // 1,048,576

    // Workspace: 32 + 8 + 96 + 32 = 168 MB (proven budget).
    char* ws = (char*)d_ws;
    short* xb    = (short*)ws;                 ws += MN * 2;        // 32 MB
    short* Wt    = (short*)ws;                 ws += WN * 2 * 4;    // 8 MB: q|k|v|o
    short* qkvB  = (short*)ws;                 ws += MN * 2 * 3;    // 96 MB: qf|kf|vv
    short* attnb = (short*)ws;                 ws += MN * 2;        // 32 MB

    short* Wto = Wt + WN * 3;
    short* qfb = qkvB;
    short* kfb = qkvB + MN;
    short* vvb = qkvB + MN * 2;

    cast_bf16<<<dim3((int)(MN / 4 / 256)), dim3(256), 0, stream>>>(x, xb, (int)(MN / 4));
    transpose_w4<<<dim3(32, 32, 4), dim3(32, 8), 0, stream>>>(W_q, W_k, W_v, W_o, Wt);

    // QKV: M=16384, N=3072 -> 64 x 12 = 768 blocks of 512 threads
    gemm256<0><<<dim3(768), dim3(512), 0, stream>>>(xb, Wt, b_q, b_k, b_v, qkvB, nullptr);

    attn_kernel<<<dim3(BATCH * NHEADS), dim3(256), 0, stream>>>(qfb, kfb, vvb, attnb);

    // O: M=16384, N=1024 -> 64 x 4 = 256 blocks
    gemm256<1><<<dim3(256), dim3(512), 0, stream>>>(attnb, Wto, b_o, nullptr, nullptr, nullptr, out);
}

// Round 7
// 332.958 us; speedup vs baseline: 1.1967x; 1.1967x over previous
//
#include <hip/hip_runtime.h>
#include <hip/hip_bf16.h>
#include <cmath>

#define D_MODEL 1024
#define NHEADS  16
#define DK      64
#define BATCH   32
#define SEQ     512
#define M_TOTAL (BATCH * SEQ)   // 16384
#define LIN_EPS 1e-6f

typedef __attribute__((ext_vector_type(8))) short short8;
typedef __attribute__((ext_vector_type(4))) short short4v;
typedef __attribute__((ext_vector_type(4))) float floatx4;

__device__ inline short f2bf(float f) {
    __hip_bfloat16 h = __float2bfloat16(f);
    return *reinterpret_cast<short*>(&h);
}
__device__ inline float bf2f(short s) {
    unsigned int u = ((unsigned int)(unsigned short)s) << 16;
    union { unsigned int u; float f; } c; c.u = u;
    return c.f;
}

#define GLL16(gptr, lptr)                                                      \
    __builtin_amdgcn_global_load_lds(                                          \
        (const __attribute__((address_space(1))) unsigned int*)(gptr),         \
        (__attribute__((address_space(3))) unsigned int*)(lptr), 16, 0, 0)

#define MFMA16(a, b, c) __builtin_amdgcn_mfma_f32_16x16x32_bf16((a), (b), (c), 0, 0, 0)

// ---------------------------------------------------------------------------
// Fused prologue: cast x fp32->bf16 (blocks 0..16383) + all four W
// transposes (blocks 16384..20479). One launch instead of two.
// ---------------------------------------------------------------------------
__global__ __launch_bounds__(256)
void prep(const float* __restrict__ x, short* __restrict__ xb,
          const float* __restrict__ W0, const float* __restrict__ W1,
          const float* __restrict__ W2, const float* __restrict__ W3,
          short* __restrict__ WtBase)
{
    __shared__ float tile[32][33];
    const int t = threadIdx.x;
    const int bid = (int)blockIdx.x;
    if (bid < 16384) {
        const int i = bid * 256 + t;               // i < 4,194,304 exactly
        float4 f = *(const float4*)&x[(size_t)i * 4];
        short4v s;
        s.x = f2bf(f.x); s.y = f2bf(f.y); s.z = f2bf(f.z); s.w = f2bf(f.w);
        *(short4v*)&xb[(size_t)i * 4] = s;
        return;
    }
    int id = bid - 16384;                          // 0..4095
    const int z = id >> 10;
    id &= 1023;
    const int bx = id & 31, by = id >> 5;
    const float* W = (z == 0) ? W0 : (z == 1) ? W1 : (z == 2) ? W2 : W3;
    short* Wt = WtBase + (size_t)z * D_MODEL * D_MODEL;
    const int tx = t & 31, ty = t >> 5;            // 32 x 8
    const int nb = bx * 32, kb = by * 32;
    #pragma unroll
    for (int r = 0; r < 32; r += 8)
        tile[ty + r][tx] = W[(size_t)(kb + ty + r) * D_MODEL + nb + tx];
    __syncthreads();
    #pragma unroll
    for (int r = 0; r < 32; r += 8)
        Wt[(size_t)(nb + ty + r) * D_MODEL + kb + tx] = f2bf(tile[tx][ty + r]);
}

// ---------------------------------------------------------------------------
// 256x256 GEMM, BK=32, QUAD-buffered LDS, counted vmcnt, L2-supertiled
// block order (R5-verified: 122us, 845 TF, 0 bank conflicts). UNCHANGED.
// MODE 0: C += bias[q|k|v]; seg<2 -> elu+1; bf16 store to [seg][B,H,N,DK].
// MODE 1: C += bias; fp32 store row-major [M][1024].
// ---------------------------------------------------------------------------
template<int MODE>
__global__ __launch_bounds__(512, 2)
void gemm256(const short* __restrict__ A, const short* __restrict__ Wt,
             const float* __restrict__ bq, const float* __restrict__ bk,
             const float* __restrict__ bv, short* __restrict__ outB,
             float* __restrict__ outF)
{
    constexpr int K   = 1024;
    constexpr int NT  = 32;                     // K-tiles of 32
    __shared__ short lds[65536];                // 128 KiB = 4 x 16384 shorts

    const int t    = threadIdx.x;
    const int wave = t >> 6;
    const int lane = t & 63;
    const int wm   = wave >> 2;                 // 0..1  -> rows wm*128
    const int wn   = wave & 3;                  // 0..3  -> cols wn*64

    // XCD-aware + L2-supertiled mapping (R5).
    const int bid = (int)blockIdx.x;
    const int xcd = bid & 7;
    const int loc = bid >> 3;
    const int g   = loc >> 5;                   // bx group
    const int r   = loc & 31;
    const int by  = xcd * 8 + (r >> 2);
    const int bx  = g * 4 + (r & 3);
    const int rowBase = by * 256;
    const int colBase = bx * 256;

    // fragment read addressing (T2 read-side swizzle)
    const int laneM = lane & 15;
    const int gq    = lane >> 4;
    const int co    = ((gq ^ ((laneM >> 1) & 3)) << 3);        // shorts
    const int aoff  = (wm * 128 + laneM) * 32 + co;            // A region +0
    const int boff  = 8192 + (wn * 64 + laneM) * 32 + co;      // B region +8192

    // staging addressing (T2 inverse swizzle on global source)
    const int stRow = t >> 2;                                   // 0..127
    const int stCol = (((t & 3) ^ ((t >> 3) & 3)) << 3);        // shorts
    const short* aSt = A  + (size_t)(rowBase + stRow) * K + stCol;
    const short* bSt = Wt + (size_t)(colBase + stRow) * K + stCol;
    const short* aSt2 = aSt + (size_t)128 * K;
    const short* bSt2 = bSt + (size_t)128 * K;
    const int dT = t * 8;                                       // shorts

    floatx4 acc[8][4];
    #pragma unroll
    for (int i = 0; i < 8; i++)
        #pragma unroll
        for (int j = 0; j < 4; j++) acc[i][j] = (floatx4){0.f, 0.f, 0.f, 0.f};

    short8 a[8], b[4];

    // prologue: tiles 0,1,2 -> bufs 0,1,2
    #pragma unroll
    for (int tt = 0; tt < 3; ++tt) {
        const int bb = tt * 16384;
        GLL16(aSt  + tt * 32, &lds[bb + dT]);
        GLL16(aSt2 + tt * 32, &lds[bb + 4096 + dT]);
        GLL16(bSt  + tt * 32, &lds[bb + 8192 + dT]);
        GLL16(bSt2 + tt * 32, &lds[bb + 8192 + 4096 + dT]);
    }

    #pragma unroll
    for (int kt = 0; kt < NT; ++kt) {
        const int cb = (kt & 3) << 14;              // current buffer (shorts)
        const int sb = ((kt + 3) & 3) << 14;        // staging target

        if (kt <= NT - 3)      asm volatile("s_waitcnt vmcnt(8)" ::: "memory");
        else if (kt == NT - 2) asm volatile("s_waitcnt vmcnt(4)" ::: "memory");
        else                   asm volatile("s_waitcnt vmcnt(0)" ::: "memory");
        __builtin_amdgcn_s_barrier();
        __builtin_amdgcn_sched_barrier(0);

        if (kt + 3 < NT) {
            GLL16(aSt  + (kt + 3) * 32, &lds[sb + dT]);
            GLL16(aSt2 + (kt + 3) * 32, &lds[sb + 4096 + dT]);
            GLL16(bSt  + (kt + 3) * 32, &lds[sb + 8192 + dT]);
            GLL16(bSt2 + (kt + 3) * 32, &lds[sb + 8192 + 4096 + dT]);
        }

        b[0] = *(const short8*)&lds[cb + boff];
        b[1] = *(const short8*)&lds[cb + boff + 512];
        #pragma unroll
        for (int i = 0; i < 4; i++)
            a[i] = *(const short8*)&lds[cb + aoff + i * 512];

        __builtin_amdgcn_s_setprio(1);
        #pragma unroll
        for (int i = 0; i < 4; i++) {
            acc[i][0] = MFMA16(a[i], b[0], acc[i][0]);
            acc[i][1] = MFMA16(a[i], b[1], acc[i][1]);
        }

        b[2] = *(const short8*)&lds[cb + boff + 1024];
        b[3] = *(const short8*)&lds[cb + boff + 1536];
        #pragma unroll
        for (int i = 0; i < 4; i++)
            a[4 + i] = *(const short8*)&lds[cb + aoff + (4 + i) * 512];

        #pragma unroll
        for (int i = 0; i < 4; i++) {
            acc[i][2] = MFMA16(a[i], b[2], acc[i][2]);
            acc[i][3] = MFMA16(a[i], b[3], acc[i][3]);
        }
        #pragma unroll
        for (int i = 0; i < 4; i++) {
            acc[4 + i][0] = MFMA16(a[4 + i], b[0], acc[4 + i][0]);
            acc[4 + i][1] = MFMA16(a[4 + i], b[1], acc[4 + i][1]);
            acc[4 + i][2] = MFMA16(a[4 + i], b[2], acc[4 + i][2]);
            acc[4 + i][3] = MFMA16(a[4 + i], b[3], acc[4 + i][3]);
        }
        __builtin_amdgcn_s_setprio(0);
    }

    // ---------------- epilogue ----------------
    if (MODE == 0) {
        const int seg = colBase >> 10;
        const float* bias = (seg == 0) ? bq : (seg == 1) ? bk : bv;
        short* outSeg = outB + (size_t)seg * ((size_t)M_TOTAL * D_MODEL);
        #pragma unroll
        for (int i = 0; i < 8; i++) {
            const int r0 = rowBase + wm * 128 + i * 16 + gq * 4;
            #pragma unroll
            for (int j = 0; j < 4; j++) {
                const int cl = (colBase & 1023) + wn * 64 + j * 16 + laneM;
                const float bvv = bias[cl];
                const int h_ = cl >> 6;
                const int d_ = cl & 63;
                #pragma unroll
                for (int reg = 0; reg < 4; reg++) {
                    float val = acc[i][j][reg] + bvv;
                    if (seg < 2) val = (val > 0.f) ? val + 1.f : expf(val);
                    const int row = r0 + reg;
                    const int b_ = row >> 9;      // SEQ=512
                    const int n_ = row & 511;
                    outSeg[((size_t)((b_ * NHEADS + h_) * SEQ + n_)) * DK + d_] = f2bf(val);
                }
            }
        }
    } else {
        #pragma unroll
        for (int i = 0; i < 8; i++) {
            const int r0 = rowBase + wm * 128 + i * 16 + gq * 4;
            #pragma unroll
            for (int j = 0; j < 4; j++) {
                const int c = colBase + wn * 64 + j * 16 + laneM;
                const float bvv = bq[c];
                #pragma unroll
                for (int reg = 0; reg < 4; reg++)
                    outF[(size_t)(r0 + reg) * 1024 + c] = acc[i][j][reg] + bvv;
            }
        }
    }
}

// ---------------------------------------------------------------------------
// Linear attention per (b,h) — R7: BOTH phases on MFMA.
//   Phase 1 (R6-verified): per 32-n tile stage kfT/vT transposed, MFMA
//   KV[d][e] = sum_n kf[n][d] v[n][e]; ksum via ones-B MFMA on wave 0.
//   NEW: KV and ksum written to LDS as hi/lo bf16 pairs
//   (hi=bf16(x), lo=bf16(x-hi) -> ~2^-16 rel err, fp32-grade).
//   Phase 2: out[n][e] = (qf @ KV) / (qf . ksum + eps) entirely on MFMA:
//   A-frag = qf straight from global (row-major K=64, the verified GEMM
//   A pattern); B = KV^T hi/lo from LDS; den = MFMA vs ksum-broadcast B
//   with C initialized to EPS. Epilogue: rcp + bf16 stores only.
//   Per wave: ~64 + 160 MFMA; VALU reduced to pack/convert/epilogue.
// ---------------------------------------------------------------------------
__global__ __launch_bounds__(256)
void attn_kernel(const short* __restrict__ qf, const short* __restrict__ kf,
                 const short* __restrict__ v, short* __restrict__ attn)
{
    __shared__ short kfT[2][64 * 40];   // [d][n-stride 40], cols 0..31 used
    __shared__ short vT [2][64 * 40];
    __shared__ short kvTh[64][72];      // [e][d], hi bf16
    __shared__ short kvTl[64][72];      // [e][d], lo bf16
    __shared__ short ksh[64];           // ksum hi bf16
    __shared__ short ksl[64];           // ksum lo bf16

    const int bh = blockIdx.x;          // 0..511
    const int b  = bh >> 4;
    const int h  = bh & 15;
    const size_t base = (size_t)bh * SEQ * DK;
    const short* qfp = qf + base;
    const short* kfp = kf + base;
    const short* vp  = v  + base;

    const int t    = threadIdx.x;
    const int wave = t >> 6;
    const int lane = t & 63;
    const int fr   = lane & 15;         // frag row/col within 16
    const int fg   = lane >> 4;         // frag k-group / acc row-group

    // phase-1 transpose-staging role: threads 0..127 kf, 128..255 v
    const int ts    = t & 127;
    const short* src = (t >> 7) ? vp : kfp;
    short* dstT0 = (t >> 7) ? &vT[0][0] : &kfT[0][0];
    short* dstT1 = (t >> 7) ? &vT[1][0] : &kfT[1][0];
    const int npair = ts & 15;          // n-pair within tile (n = npair*2)
    const int d0s   = (ts >> 4) * 8;    // d slice

    floatx4 accKV[4], accKS[4];
    #pragma unroll
    for (int m = 0; m < 4; ++m) {
        accKV[m] = (floatx4){0.f, 0.f, 0.f, 0.f};
        accKS[m] = (floatx4){0.f, 0.f, 0.f, 0.f};
    }
    short8 ones;
    #pragma unroll
    for (int j = 0; j < 8; ++j) ones[j] = (short)0x3F80;   // bf16 1.0

    short8 r0 = *(const short8*)&src[(size_t)(npair * 2) * DK + d0s];
    short8 r1 = *(const short8*)&src[(size_t)(npair * 2 + 1) * DK + d0s];

    #pragma unroll
    for (int tt = 0; tt < 16; ++tt) {
        short* dstT = (tt & 1) ? dstT1 : dstT0;
        #pragma unroll
        for (int j = 0; j < 8; ++j) {
            unsigned int pk = (unsigned int)(unsigned short)r0[j]
                            | ((unsigned int)(unsigned short)r1[j] << 16);
            *(unsigned int*)&dstT[(d0s + j) * 40 + npair * 2] = pk;
        }
        if (tt < 15) {
            const int n0 = (tt + 1) * 32;
            r0 = *(const short8*)&src[(size_t)(n0 + npair * 2) * DK + d0s];
            r1 = *(const short8*)&src[(size_t)(n0 + npair * 2 + 1) * DK + d0s];
        }
        __syncthreads();
        const short* kB = (tt & 1) ? &kfT[1][0] : &kfT[0][0];
        const short* vB = (tt & 1) ? &vT[1][0]  : &vT[0][0];
        short8 bf = *(const short8*)&vB[(wave * 16 + fr) * 40 + fg * 8];
        #pragma unroll
        for (int m = 0; m < 4; ++m) {
            short8 af = *(const short8*)&kB[(m * 16 + fr) * 40 + fg * 8];
            accKV[m] = MFMA16(af, bf, accKV[m]);
            if (wave == 0) accKS[m] = MFMA16(af, ones, accKS[m]);
        }
        // buffer tt&1 is rewritten only at tt+2, after the tt+1 barrier;
        // all its reads were consumed by the MFMAs above (before it).
    }

    // KV C/D layout (verified): row d = m*16+fg*4+reg, col e = wave*16+fr.
    // Write transposed hi/lo: kvT[e][d].
    #pragma unroll
    for (int m = 0; m < 4; ++m) {
        short4v hi4, lo4;
        #pragma unroll
        for (int reg = 0; reg < 4; ++reg) {
            const float x = accKV[m][reg];
            const short hs = f2bf(x);
            hi4[reg] = hs;
            lo4[reg] = f2bf(x - bf2f(hs));
        }
        *(short4v*)&kvTh[wave * 16 + fr][m * 16 + fg * 4] = hi4;
        *(short4v*)&kvTl[wave * 16 + fr][m * 16 + fg * 4] = lo4;
    }
    if (wave == 0 && fr == 0) {
        #pragma unroll
        for (int m = 0; m < 4; ++m)
            #pragma unroll
            for (int reg = 0; reg < 4; ++reg) {
                const float x = accKS[m][reg];
                const short hs = f2bf(x);
                ksh[m * 16 + fg * 4 + reg] = hs;
                ksl[m * 16 + fg * 4 + reg] = f2bf(x - bf2f(hs));
            }
    }
    __syncthreads();

    // ---------------- phase 2: pure MFMA ----------------
    // A-frags: qf rows from global. Wave owns n in [wave*128, wave*128+128).
    short8 aq[8][2];
    const int nb0 = wave * 128;
    #pragma unroll
    for (int m = 0; m < 8; ++m) {
        aq[m][0] = *(const short8*)&qfp[(size_t)(nb0 + m * 16 + fr) * DK + fg * 8];
        aq[m][1] = *(const short8*)&qfp[(size_t)(nb0 + m * 16 + fr) * DK + 32 + fg * 8];
    }
    // B-frags: KV^T hi/lo + ksum broadcast
    short8 bvh[4][2], bvl[4][2], bsh[2], bsl[2];
    #pragma unroll
    for (int j = 0; j < 4; ++j)
        #pragma unroll
        for (int k = 0; k < 2; ++k) {
            bvh[j][k] = *(const short8*)&kvTh[j * 16 + fr][k * 32 + fg * 8];
            bvl[j][k] = *(const short8*)&kvTl[j * 16 + fr][k * 32 + fg * 8];
        }
    #pragma unroll
    for (int k = 0; k < 2; ++k) {
        bsh[k] = *(const short8*)&ksh[k * 32 + fg * 8];   // same for all fr
        bsl[k] = *(const short8*)&ksl[k * 32 + fg * 8];
    }

    short* dstBase = attn + ((size_t)(b * SEQ)) * D_MODEL + h * DK;
    #pragma unroll
    for (int m = 0; m < 8; ++m) {
        const int n0 = nb0 + m * 16;
        floatx4 o[4];
        floatx4 dn = (floatx4){LIN_EPS, LIN_EPS, LIN_EPS, LIN_EPS};
        #pragma unroll
        for (int j = 0; j < 4; ++j) o[j] = (floatx4){0.f, 0.f, 0.f, 0.f};
        #pragma unroll
        for (int k = 0; k < 2; ++k) {
            #pragma unroll
            for (int j = 0; j < 4; ++j) {
                o[j] = MFMA16(aq[m][k], bvh[j][k], o[j]);
                o[j] = MFMA16(aq[m][k], bvl[j][k], o[j]);
            }
            dn = MFMA16(aq[m][k], bsh[k], dn);
            dn = MFMA16(aq[m][k], bsl[k], dn);
        }
        // C/D: row n = n0 + fg*4 + reg, col e = j*16 + fr
        #pragma unroll
        for (int reg = 0; reg < 4; ++reg) {
            const float inv = 1.f / dn[reg];
            short* dst = dstBase + (size_t)(n0 + fg * 4 + reg) * D_MODEL;
            #pragma unroll
            for (int j = 0; j < 4; ++j)
                dst[j * 16 + fr] = f2bf(o[j][reg] * inv);
        }
    }
}

extern "C" void kernel_launch(void* const* d_in, const int* in_sizes, int n_in,
                              void* d_out, int out_size, void* d_ws, size_t ws_size,
                              hipStream_t stream)
{
    const float* x   = (const float*)d_in[0];
    const float* W_q = (const float*)d_in[1];
    const float* b_q = (const float*)d_in[2];
    const float* W_k = (const float*)d_in[3];
    const float* b_k = (const float*)d_in[4];
    const float* W_v = (const float*)d_in[5];
    const float* b_v = (const float*)d_in[6];
    const float* W_o = (const float*)d_in[7];
    const float* b_o = (const float*)d_in[8];
    float* out = (float*)d_out;

    const size_t MN = (size_t)M_TOTAL * D_MODEL;   // 16,777,216
    const size_t WN = (size_t)D_MODEL * D_MODEL;   // 1,048,576

    // Workspace: 32 + 8 + 96 + 32 = 168 MB (proven budget).
    char* ws = (char*)d_ws;
    short* xb    = (short*)ws;                 ws += MN * 2;        // 32 MB
    short* Wt    = (short*)ws;                 ws += WN * 2 * 4;    // 8 MB: q|k|v|o
    short* qkvB  = (short*)ws;                 ws += MN * 2 * 3;    // 96 MB: qf|kf|vv
    short* attnb = (short*)ws;                 ws += MN * 2;        // 32 MB

    short* Wto = Wt + WN * 3;
    short* qfb = qkvB;
    short* kfb = qkvB + MN;
    short* vvb = qkvB + MN * 2;

    // fused cast + weight transposes: 16384 + 4096 blocks
    prep<<<dim3(20480), dim3(256), 0, stream>>>(x, xb, W_q, W_k, W_v, W_o, Wt);

    // QKV: M=16384, N=3072 -> 768 blocks of 512 threads
    gemm256<0><<<dim3(768), dim3(512), 0, stream>>>(xb, Wt, b_q, b_k, b_v, qkvB, nullptr);

    attn_kernel<<<dim3(BATCH * NHEADS), dim3(256), 0, stream>>>(qfb, kfb, vvb, attnb);

    // O: M=16384, N=1024 -> 256 blocks
    gemm256<1><<<dim3(256), dim3(512), 0, stream>>>(attnb, Wto, b_o, nullptr, nullptr, nullptr, out);
}